// Round 4
// baseline (7191.010 us; speedup 1.0000x reference)
//
#include <hip/hip_runtime.h>

// EncoderLSTMContinuous v7: LDS-direct weight DMA pipeline.
// v3/v6 post-mortem arithmetic: per-wave in-flight weight bytes are VGPR-capped
// (~450B/wave, ~3.6KB/CU) -> at ~400cy L2/L3 latency effective BW ~9B/cyc/CU
// -> 155us/step, matching the measured 133us/step. More waves failed twice
// (v4 compiler VGPR cap, v5 no co-residency); register prefetch failed (v6,
// compiler re-serialized). v7 uses __builtin_amdgcn_global_load_lds(16B):
// outstanding bytes tracked in vmcnt, not VGPRs. 2x32KB LDS chunk ring,
// per-wave-private 4KB slices (4 DMA instrs/chunk, no barriers added),
// counted s_waitcnt vmcnt(4) (never 0 in loop), next-sweep chunk0 issued from
// the tail of each sweep. s_xh moved to registers (8 VGPR) to fit LDS=143.4KB.
// MFMA k-order identical to v3 -> bitwise-same accumulation.

typedef _Float16 half_t;
typedef _Float16 half8 __attribute__((ext_vector_type(8)));
typedef _Float16 half4v __attribute__((ext_vector_type(4)));
typedef float float4_ __attribute__((ext_vector_type(4)));

#define UNITS 512
#define IN_DIM 1024
#define NROWS 8192
#define DEPTH 32
#define ZK 256
#define MT 32
#define PITCH (UNITS + 8)    // 520 halves
#define XPITCH (IN_DIM + 8)
#define RING_H 16384         // halves per ring buffer (32KB); 2 buffers

__device__ __forceinline__ float4_ mfma16(half8 a, half8 b, float4_ c) {
  // D[m][n]: m=(lane>>4)*4+reg, n=lane&15. A[m=lane&15][k=(lane>>4)*8+j], B[k][n=lane&15].
  return __builtin_amdgcn_mfma_f32_16x16x32_f16(a, b, c, 0, 0, 0);
}
__device__ __forceinline__ float fast_sigmoid(float x) {
  return __builtin_amdgcn_rcpf(1.0f + __builtin_amdgcn_exp2f(-1.4426950408889634f * x));
}
__device__ __forceinline__ float fast_tanh(float x) {
  return 2.0f * __builtin_amdgcn_rcpf(1.0f + __builtin_amdgcn_exp2f(-2.8853900817779268f * x)) - 1.0f;
}
// 16B global->LDS DMA. Global src per-lane; LDS dest wave-uniform base + lane*16.
__device__ __forceinline__ void gload_lds16(const half_t* g, half_t* l) {
  __builtin_amdgcn_global_load_lds((const __attribute__((address_space(1))) void*)g,
                                   (__attribute__((address_space(3))) void*)l, 16, 0, 0);
}

// 16-chunk pipelined sweep, k-width 32 halves. Per chunk: 4 DMA (next chunk),
// vmcnt(4), 4 weight ds_read_b128, 2 act ds_read_b128, 8 MFMA.
// Precondition: chunk 0 already issued into ring buf0. Postcondition: next
// sweep's chunk 0 issued (via next()).
template<class IssueF, class NextF>
__device__ __forceinline__ void sweep32(IssueF issueK, NextF next, int wread,
                                        half_t* sl0, const half_t* abase,
                                        float4_ (&acc)[4][2]) {
#pragma unroll
  for (int kc = 0; kc < 16; ++kc) {
    if (kc < 15) issueK(kc + 1, (kc + 1) & 1);
    else next();
    asm volatile("s_waitcnt vmcnt(4)" ::: "memory");
    const half_t* wsl = sl0 + (kc & 1) * RING_H;
    half8 wv[4];
#pragma unroll
    for (int j = 0; j < 4; ++j) wv[j] = *(const half8*)(wsl + j * 512 + wread);
    half8 a0 = *(const half8*)(abase + kc * 32);
    half8 a1 = *(const half8*)(abase + 16 * PITCH + kc * 32);
#pragma unroll
    for (int j = 0; j < 4; ++j) {
      acc[j][0] = mfma16(wv[j], a0, acc[j][0]);
      acc[j][1] = mfma16(wv[j], a1, acc[j][1]);
    }
  }
}

// 8-chunk sweep for yW, k-width 64 halves. DMA slot j: colblk i=j&1, kk=j>>1.
template<class IssueF, class NextF>
__device__ __forceinline__ void sweep64y(IssueF issueK, NextF next, int wread,
                                         half_t* sl0, const half_t* abase,
                                         float4_ (&acc)[2][2]) {
#pragma unroll
  for (int kc = 0; kc < 8; ++kc) {
    if (kc < 7) issueK(kc + 1, (kc + 1) & 1);
    else next();
    asm volatile("s_waitcnt vmcnt(4)" ::: "memory");
    const half_t* wsl = sl0 + (kc & 1) * RING_H;
    half8 wv[4];
#pragma unroll
    for (int j = 0; j < 4; ++j) wv[j] = *(const half8*)(wsl + j * 512 + wread);
#pragma unroll
    for (int rb = 0; rb < 2; ++rb) {
      half8 ak0 = *(const half8*)(abase + rb * 16 * PITCH + kc * 64);
      half8 ak1 = *(const half8*)(abase + rb * 16 * PITCH + kc * 64 + 32);
      acc[0][rb] = mfma16(wv[0], ak0, acc[0][rb]);
      acc[1][rb] = mfma16(wv[1], ak0, acc[1][rb]);
      acc[0][rb] = mfma16(wv[2], ak1, acc[0][rb]);
      acc[1][rb] = mfma16(wv[3], ak1, acc[1][rb]);
    }
  }
}

// ---- old-orientation helper for xh_kernel (acts=A, weights=B)
template<int NB, int K, int AP, class OffF>
__device__ inline void stage_gemm(const half_t* __restrict__ bbase, OffF off,
                                  const half_t* __restrict__ A, int q, int c16,
                                  float4_ (&acc)[NB][2]) {
#pragma unroll
  for (int nb = 0; nb < NB; ++nb) {
    acc[nb][0] = {0.f, 0.f, 0.f, 0.f};
    acc[nb][1] = {0.f, 0.f, 0.f, 0.f};
  }
  for (int k0 = 0; k0 < K; k0 += 64) {
    const half_t* ap = A + c16 * AP + k0 + q * 8;
    half8 a00 = *(const half8*)(ap);
    half8 a01 = *(const half8*)(ap + 32);
    half8 a10 = *(const half8*)(ap + 16 * AP);
    half8 a11 = *(const half8*)(ap + 16 * AP + 32);
#pragma unroll
    for (int nb = 0; nb < NB; ++nb) {
      const half_t* bp = bbase + off(nb) + k0;
      half8 b0 = *(const half8*)(bp);
      half8 b1 = *(const half8*)(bp + 32);
      acc[nb][0] = mfma16(a00, b0, acc[nb][0]);
      acc[nb][0] = mfma16(a01, b1, acc[nb][0]);
      acc[nb][1] = mfma16(a10, b0, acc[nb][1]);
      acc[nb][1] = mfma16(a11, b1, acc[nb][1]);
    }
  }
}

// ---- prep: fp32 [R][C] -> fp16 [C][R] tiled transpose-convert
__global__ void transpose_convert(const float* __restrict__ in, half_t* __restrict__ out,
                                  int R, int C) {
  __shared__ float tile[32][33];
  int c0 = blockIdx.x * 32, r0 = blockIdx.y * 32;
  int tx = threadIdx.x, ty = threadIdx.y;
#pragma unroll
  for (int i = 0; i < 32; i += 8)
    tile[ty + i][tx] = in[(size_t)(r0 + ty + i) * C + c0 + tx];
  __syncthreads();
#pragma unroll
  for (int i = 0; i < 32; i += 8)
    out[(size_t)(c0 + ty + i) * R + r0 + tx] = (half_t)tile[tx][ty + i];
}

// ---- one-time xh = x @ h_W + h_b  (fp16 out, h_b folded in)
__global__ __launch_bounds__(512, 2) void xh_kernel(
    const float* __restrict__ x, const half_t* __restrict__ hW_T,
    const float* __restrict__ h_b, half_t* __restrict__ xh_g) {
  extern __shared__ half_t sx[];
  const int tid = threadIdx.x;
  const int w = tid >> 6, l = tid & 63, q = l >> 4, c16 = l & 15;
  const int row0 = blockIdx.x * 32;
  for (int it = tid; it < 32 * IN_DIM / 4; it += 512) {
    int r = it >> 8;
    int c = (it & 255) * 4;
    float4_ v = __builtin_nontemporal_load((const float4_*)(x + (size_t)(row0 + r) * IN_DIM + c));
    half4v hv;
    hv[0] = (half_t)v[0]; hv[1] = (half_t)v[1]; hv[2] = (half_t)v[2]; hv[3] = (half_t)v[3];
    *(half4v*)(sx + r * XPITCH + c) = hv;
  }
  __syncthreads();
  const int n0 = w * 64;
  float4_ acc[4][2];
  const half_t* bbase = hW_T + (size_t)(n0 + c16) * IN_DIM + q * 8;
  stage_gemm<4, IN_DIM, XPITCH>(bbase, [](int nb) { return nb * 16 * IN_DIM; }, sx, q, c16, acc);
#pragma unroll
  for (int nb = 0; nb < 4; ++nb)
#pragma unroll
    for (int mb = 0; mb < 2; ++mb)
#pragma unroll
      for (int r = 0; r < 4; ++r) {
        int row = mb * 16 + q * 4 + r;
        int col = n0 + nb * 16 + c16;
        xh_g[(size_t)(row0 + row) * UNITS + col] = (half_t)(acc[nb][mb][r] + h_b[col]);
      }
}

// ---- the persistent scan kernel (MT=32, 256 WGs, 8 waves each, 1 WG/CU)
__global__ __launch_bounds__(512, 2) void lstm_main(
    const half_t* __restrict__ xh_g, const half_t* __restrict__ hU_T,
    const half_t* __restrict__ W4_T, const half_t* __restrict__ tW_T,
    const half_t* __restrict__ yW_T,
    const float* __restrict__ f_b, const float* __restrict__ i_b,
    const float* __restrict__ c_b, const float* __restrict__ o_b,
    const float* __restrict__ t_b, const float* __restrict__ y_b,
    const float* __restrict__ h0, float* __restrict__ out) {
  extern __shared__ half_t smem[];
  half_t* bufA = smem;                 // state -> (o*h1) -> state
  half_t* bufB = smem + MT * PITCH;    // h -> t
  float* s_bias = (float*)(smem + 2 * MT * PITCH);      // f,i,c,o,t (512 ea) + y (256)
  float* s_fb = s_bias;
  float* s_ib = s_bias + 512;
  float* s_cb = s_bias + 1024;
  float* s_ob = s_bias + 1536;
  float* s_tb = s_bias + 2048;
  float* s_yb = s_bias + 2560;
  half_t* ring = smem + 2 * MT * PITCH + 2816 * 2;      // 2 x 32KB chunk ring

  const int tid = threadIdx.x;
  const int w = tid >> 6, l = tid & 63, q = l >> 4, c16 = l & 15;
  const int row0 = blockIdx.x * MT;
  half_t* sl0 = ring + w * 2048;             // this wave's 4KB slice in buf0
  const int laneoff = c16 * 1024 + q * 16;   // per-lane byte offset in a 16-row group
  const int wread = q * 128 + c16 * 8;       // ds_read offset (halves) within slice

  // init bufA = broadcast h0 (fp16); biases
  for (int it = tid; it < MT * UNITS / 8; it += 512) {
    int r = it >> 6;
    int c = (it & 63) * 8;
    float4_ v0 = *(const float4_*)(h0 + c);
    float4_ v1 = *(const float4_*)(h0 + c + 4);
    half8 hv;
#pragma unroll
    for (int j = 0; j < 4; ++j) { hv[j] = (half_t)v0[j]; hv[4 + j] = (half_t)v1[j]; }
    *(half8*)(bufA + r * PITCH + c) = hv;
  }
  {
    int it = tid;
    s_fb[it] = f_b[it]; s_ib[it] = i_b[it]; s_cb[it] = c_b[it]; s_ob[it] = o_b[it];
    s_tb[it] = t_b[it];
    if (it < 256) s_yb[it] = y_b[it];
  }
  // xh in registers: 8 x half4v per thread (replaces s_xh; frees 33KB LDS)
  half4v xh_r[4][2];
#pragma unroll
  for (int cm = 0; cm < 4; ++cm)
#pragma unroll
    for (int rb = 0; rb < 2; ++rb)
      xh_r[cm][rb] = *(const half4v*)(xh_g + (size_t)(row0 + rb * 16 + c16) * UNITS +
                                      w * 64 + cm * 16 + q * 4);
  // state registers: row = rb*16 + c16, col = hh*256 + w*32 + cm*16 + q*4 + r
  half4v state_r[2][2][2];
#pragma unroll
  for (int hh = 0; hh < 2; ++hh)
#pragma unroll
    for (int cm = 0; cm < 2; ++cm) {
      int col0 = hh * 256 + w * 32 + cm * 16 + q * 4;
      float4_ v = *(const float4_*)(h0 + col0);
      half4v s4;
#pragma unroll
      for (int r = 0; r < 4; ++r) s4[r] = (half_t)v[r];
#pragma unroll
      for (int rb = 0; rb < 2; ++rb) state_r[hh][cm][rb] = s4;
    }
  __syncthreads();

  const char* hU_c = (const char*)hU_T;
  const char* W4_c = (const char*)W4_T;
  const char* tW_c = (const char*)tW_T;
  const char* yW_c = (const char*)yW_T;

  // issue 4 DMA instrs (one chunk slice) from g0 (+row-group byte offsets) into ring buf
  auto iss = [&](const char* g0, int b0, int b1, int b2, int b3, int buf) {
    half_t* d = sl0 + buf * RING_H;
    gload_lds16((const half_t*)(g0 + b0), d);
    gload_lds16((const half_t*)(g0 + b1), d + 512);
    gload_lds16((const half_t*)(g0 + b2), d + 1024);
    gload_lds16((const half_t*)(g0 + b3), d + 1536);
  };
  const int bA0 = (w * 64) * 1024, bA1 = (w * 64 + 16) * 1024,
            bA2 = (w * 64 + 32) * 1024, bA3 = (w * 64 + 48) * 1024;
  auto isHU = [&](int kc, int buf) { iss(hU_c + kc * 64 + laneoff, bA0, bA1, bA2, bA3, buf); };
  auto isTW = [&](int kc, int buf) { iss(tW_c + kc * 64 + laneoff, bA0, bA1, bA2, bA3, buf); };
  auto s2b = [&](int hh, int p, int j) {
    return ((2 * p + (j >> 1)) * 512 + hh * 256 + w * 32 + (j & 1) * 16) * 1024;
  };
  auto isW4 = [&](int hh, int p, int kc, int buf) {
    iss(W4_c + kc * 64 + laneoff, s2b(hh, p, 0), s2b(hh, p, 1), s2b(hh, p, 2), s2b(hh, p, 3), buf);
  };
  const int bY0 = (w * 32) * 1024, bY1 = (w * 32 + 16) * 1024;
  auto isYW = [&](int kc, int buf) {
    iss(yW_c + kc * 128 + laneoff, bY0, bY1, bY0 + 64, bY1 + 64, buf);
  };
  // gate epilogue for one hh half (called with literal hh -> const-folds)
  auto gates = [&](int hh, float4_ (&a8)[2][4][2]) {
#pragma unroll
    for (int cm = 0; cm < 2; ++cm) {
      int col0 = hh * 256 + w * 32 + cm * 16 + q * 4;
      float4_ fb4 = *(const float4_*)(s_fb + col0);
      float4_ ib4 = *(const float4_*)(s_ib + col0);
      float4_ cb4 = *(const float4_*)(s_cb + col0);
      float4_ ob4 = *(const float4_*)(s_ob + col0);
#pragma unroll
      for (int rb = 0; rb < 2; ++rb) {
        int row = rb * 16 + c16;
        half4v hp = state_r[hh][cm][rb];
        half4v h1v, sbv;
#pragma unroll
        for (int r = 0; r < 4; ++r) {
          float gf = fast_sigmoid(a8[0][cm][rb][r] + fb4[r]);
          float gi = fast_sigmoid(a8[0][2 + cm][rb][r] + ib4[r]);
          float gc = fast_tanh   (a8[1][cm][rb][r] + cb4[r]);
          float go = fast_sigmoid(a8[1][2 + cm][rb][r] + ob4[r]);
          float h1 = (float)hp[r] * gf + gc * gi;
          h1v[r] = (half_t)h1;
          sbv[r] = (half_t)(go * h1);
        }
        state_r[hh][cm][rb] = h1v;
        *(half4v*)(bufA + row * PITCH + col0) = sbv;
      }
    }
  };

  isHU(0, 0);  // prime the pipeline: step-0 stage-1 chunk 0
  for (int s = 0; s < DEPTH; ++s) {
    // ---- stage 1: h = tanh(xh + state @ h_U) : read bufA -> write bufB
    {
      float4_ acc[4][2];
#pragma unroll
      for (int i = 0; i < 4; ++i) { acc[i][0] = {0.f,0.f,0.f,0.f}; acc[i][1] = {0.f,0.f,0.f,0.f}; }
      sweep32(isHU, [&] { isW4(0, 0, 0, 0); }, wread, sl0, bufA + c16 * PITCH + q * 8, acc);
#pragma unroll
      for (int cm = 0; cm < 4; ++cm) {
        int col0 = w * 64 + cm * 16 + q * 4;
#pragma unroll
        for (int rb = 0; rb < 2; ++rb) {
          int row = rb * 16 + c16;
          half4v hv;
#pragma unroll
          for (int r = 0; r < 4; ++r)
            hv[r] = (half_t)fast_tanh(acc[cm][rb][r] + (float)xh_r[cm][rb][r]);
          *(half4v*)(bufB + row * PITCH + col0) = hv;
        }
      }
    }
    __syncthreads();
    // ---- stage 2: gates from h (bufB); 4 chained sub-sweeps (hh x matrix-pair)
    {
      const half_t* ab = bufB + c16 * PITCH + q * 8;
      float4_ a8[2][4][2];
#pragma unroll
      for (int p = 0; p < 2; ++p)
#pragma unroll
        for (int i = 0; i < 4; ++i) { a8[p][i][0] = {0.f,0.f,0.f,0.f}; a8[p][i][1] = {0.f,0.f,0.f,0.f}; }
      sweep32([&](int kc, int b) { isW4(0, 0, kc, b); }, [&] { isW4(0, 1, 0, 0); },
              wread, sl0, ab, a8[0]);
      sweep32([&](int kc, int b) { isW4(0, 1, kc, b); }, [&] { isW4(1, 0, 0, 0); },
              wread, sl0, ab, a8[1]);
      gates(0, a8);
#pragma unroll
      for (int p = 0; p < 2; ++p)
#pragma unroll
        for (int i = 0; i < 4; ++i) { a8[p][i][0] = {0.f,0.f,0.f,0.f}; a8[p][i][1] = {0.f,0.f,0.f,0.f}; }
      sweep32([&](int kc, int b) { isW4(1, 0, kc, b); }, [&] { isW4(1, 1, 0, 0); },
              wread, sl0, ab, a8[0]);
      sweep32([&](int kc, int b) { isW4(1, 1, kc, b); }, [&] { isTW(0, 0); },
              wread, sl0, ab, a8[1]);
      gates(1, a8);
    }
    __syncthreads();
    // ---- stage 3: t = tanh((o*h1) @ t_W + t_b) : read bufA -> write bufB
    {
      float4_ acc[4][2];
#pragma unroll
      for (int i = 0; i < 4; ++i) { acc[i][0] = {0.f,0.f,0.f,0.f}; acc[i][1] = {0.f,0.f,0.f,0.f}; }
      sweep32(isTW, [&] { isYW(0, 0); }, wread, sl0, bufA + c16 * PITCH + q * 8, acc);
#pragma unroll
      for (int cm = 0; cm < 4; ++cm) {
        int col0 = w * 64 + cm * 16 + q * 4;
        float4_ tb4 = *(const float4_*)(s_tb + col0);
#pragma unroll
        for (int rb = 0; rb < 2; ++rb) {
          int row = rb * 16 + c16;
          half4v hv;
#pragma unroll
          for (int r = 0; r < 4; ++r) hv[r] = (half_t)fast_tanh(acc[cm][rb][r] + tb4[r]);
          *(half4v*)(bufB + row * PITCH + col0) = hv;
        }
      }
    }
    __syncthreads();
    // ---- stage 4: y = tanh(t @ y_W + y_b) -> nt-store out ; state regs -> bufA
    {
      float4_ acc[2][2];
#pragma unroll
      for (int i = 0; i < 2; ++i) { acc[i][0] = {0.f,0.f,0.f,0.f}; acc[i][1] = {0.f,0.f,0.f,0.f}; }
      sweep64y(isYW, [&] { isHU(0, 0); }, wread, sl0, bufB + c16 * PITCH + q * 8, acc);
#pragma unroll
      for (int cm = 0; cm < 2; ++cm) {
        int col0 = w * 32 + cm * 16 + q * 4;
        float4_ yb4 = *(const float4_*)(s_yb + col0);
#pragma unroll
        for (int rb = 0; rb < 2; ++rb) {
          int row = rb * 16 + c16;
          float4_ yv;
#pragma unroll
          for (int r = 0; r < 4; ++r) yv[r] = fast_tanh(acc[cm][rb][r] + yb4[r]);
          __builtin_nontemporal_store(yv,
              (float4_*)(out + ((size_t)(row0 + row) * DEPTH + s) * ZK + col0));
        }
      }
#pragma unroll
      for (int hh = 0; hh < 2; ++hh)
#pragma unroll
        for (int cm = 0; cm < 2; ++cm) {
          int col0 = hh * 256 + w * 32 + cm * 16 + q * 4;
#pragma unroll
          for (int rb = 0; rb < 2; ++rb)
            *(half4v*)(bufA + (rb * 16 + c16) * PITCH + col0) = state_r[hh][cm][rb];
        }
    }
    __syncthreads();
  }
}

extern "C" void kernel_launch(void* const* d_in, const int* in_sizes, int n_in,
                              void* d_out, int out_size, void* d_ws, size_t ws_size,
                              hipStream_t stream) {
  (void)in_sizes; (void)n_in; (void)out_size; (void)ws_size;
  const float* x   = (const float*)d_in[0];
  const float* h_W = (const float*)d_in[1];
  const float* h_U = (const float*)d_in[2];
  const float* h_b = (const float*)d_in[3];
  const float* f_W = (const float*)d_in[4];
  const float* f_b = (const float*)d_in[5];
  const float* i_W = (const float*)d_in[6];
  const float* i_b = (const float*)d_in[7];
  const float* c_W = (const float*)d_in[8];
  const float* c_b = (const float*)d_in[9];
  const float* o_W = (const float*)d_in[10];
  const float* o_b = (const float*)d_in[11];
  const float* t_W = (const float*)d_in[12];
  const float* t_b = (const float*)d_in[13];
  const float* y_W = (const float*)d_in[14];
  const float* y_b = (const float*)d_in[15];
  const float* h0  = (const float*)d_in[16];
  float* out = (float*)d_out;

  half_t* ws   = (half_t*)d_ws;
  half_t* hW_T = ws;                                   // [512][1024]
  half_t* hU_T = hW_T + (size_t)UNITS * IN_DIM;        // [512][512]
  half_t* W4_T = hU_T + (size_t)UNITS * UNITS;         // [2048][512] f,i,c,o
  half_t* tW_T = W4_T + (size_t)4 * UNITS * UNITS;     // [512][512]
  half_t* yW_T = tW_T + (size_t)UNITS * UNITS;         // [256][512]
  half_t* xh_g = yW_T + (size_t)ZK * UNITS;            // [8192][512]

  // bufA,bufB (66,560B) + biases (11,264B) + ring 2x32KB (65,536B) = 143,360B
  const int lds_main = 2 * MT * PITCH * 2 + 2816 * 4 + 2 * RING_H * 2;
  hipFuncSetAttribute((const void*)xh_kernel, hipFuncAttributeMaxDynamicSharedMemorySize,
                      32 * XPITCH * 2);
  hipFuncSetAttribute((const void*)lstm_main, hipFuncAttributeMaxDynamicSharedMemorySize,
                      lds_main);

  dim3 tb(32, 8);
  hipLaunchKernelGGL(transpose_convert, dim3(UNITS / 32, IN_DIM / 32), tb, 0, stream,
                     h_W, hW_T, IN_DIM, UNITS);
  hipLaunchKernelGGL(transpose_convert, dim3(UNITS / 32, UNITS / 32), tb, 0, stream,
                     h_U, hU_T, UNITS, UNITS);
  hipLaunchKernelGGL(transpose_convert, dim3(UNITS / 32, UNITS / 32), tb, 0, stream,
                     f_W, W4_T + 0 * (size_t)UNITS * UNITS, UNITS, UNITS);
  hipLaunchKernelGGL(transpose_convert, dim3(UNITS / 32, UNITS / 32), tb, 0, stream,
                     i_W, W4_T + 1 * (size_t)UNITS * UNITS, UNITS, UNITS);
  hipLaunchKernelGGL(transpose_convert, dim3(UNITS / 32, UNITS / 32), tb, 0, stream,
                     c_W, W4_T + 2 * (size_t)UNITS * UNITS, UNITS, UNITS);
  hipLaunchKernelGGL(transpose_convert, dim3(UNITS / 32, UNITS / 32), tb, 0, stream,
                     o_W, W4_T + 3 * (size_t)UNITS * UNITS, UNITS, UNITS);
  hipLaunchKernelGGL(transpose_convert, dim3(UNITS / 32, UNITS / 32), tb, 0, stream,
                     t_W, tW_T, UNITS, UNITS);
  hipLaunchKernelGGL(transpose_convert, dim3(ZK / 32, UNITS / 32), tb, 0, stream,
                     y_W, yW_T, UNITS, ZK);
  hipLaunchKernelGGL(xh_kernel, dim3(NROWS / 32), dim3(512), 32 * XPITCH * 2, stream,
                     x, hW_T, h_b, xh_g);
  hipLaunchKernelGGL(lstm_main, dim3(NROWS / MT), dim3(512), lds_main, stream,
                     xh_g, hU_T, W4_T, tW_T, yW_T, f_b, i_b, c_b, o_b, t_b, y_b, h0, out);
}